// Round 12
// baseline (661.310 us; speedup 1.0000x reference)
//
#include <hip/hip_runtime.h>
#include <math.h>

// Problem constants
#define TEMP 0.7f
#define TOPK 50
#define TOPP 0.9f
#define M_TOT 2048      // B*S
#define K_DIM 512       // H
#define V_DIM 50257     // vocab
#define NPAD 50304      // 393*128
#define KP 1536         // 3*K_DIM: [hi|hi|lo] x [hi|lo|hi]
#define BM 256
#define BN 128
#define BKE 64
#define NSTEP (KP / BKE)
#define NBN (NPAD / BN)  // 393 N-tiles
#define NBM (M_TOT / BM) // 8 M-tiles

typedef short s16x8 __attribute__((ext_vector_type(8)));
typedef float f32x4 __attribute__((ext_vector_type(4)));

#define MFMA_16x16x32_BF16(acc, va, vb) \
  asm("v_mfma_f32_16x16x32_bf16 %0, %1, %2, %0" : "+v"(acc) : "v"(va), "v"(vb))

__device__ __forceinline__ unsigned short bf16_rn(float x) {
  unsigned u = __float_as_uint(x);
  unsigned r = u + 0x7FFFu + ((u >> 16) & 1u);
  return (unsigned short)(r >> 16);
}
__device__ __forceinline__ float bf16_to_f(unsigned short h) {
  return __uint_as_float(((unsigned)h) << 16);
}
__device__ __forceinline__ unsigned f2key(float f) {
  unsigned u = __float_as_uint(f);
  return (u & 0x80000000u) ? ~u : (u | 0x80000000u);
}

// ------------- fused conversion: X -> [hi|hi|lo], W -> [hi|lo|hi] -------------
#define NQX (M_TOT * (K_DIM / 4))
#define NQW (NPAD * (K_DIM / 4))

__global__ __launch_bounds__(256) void conv_kernel(const float* __restrict__ X,
                                                   const float* __restrict__ W,
                                                   unsigned short* __restrict__ Xp,
                                                   unsigned short* __restrict__ Wp) {
  int idx = blockIdx.x * 256 + threadIdx.x;
  float4 v;
  unsigned short* dst;
  size_t base;
  int mode;
  if (idx < NQX) {
    int row = idx >> 7, q = idx & 127;
    v = reinterpret_cast<const float4*>(X)[idx];
    dst = Xp;
    base = (size_t)row * KP + q * 4;
    mode = 0;
  } else {
    int wi = idx - NQX;
    if (wi >= NQW) return;
    int row = wi >> 7, q = wi & 127;
    v = make_float4(0.f, 0.f, 0.f, 0.f);
    if (row < V_DIM) v = reinterpret_cast<const float4*>(W)[(size_t)row * 128 + q];
    dst = Wp;
    base = (size_t)row * KP + q * 4;
    mode = 1;
  }
  float vv[4] = {v.x, v.y, v.z, v.w};
  unsigned short hi[4], lo[4];
#pragma unroll
  for (int j = 0; j < 4; ++j) {
    hi[j] = bf16_rn(vv[j]);
    lo[j] = bf16_rn(vv[j] - bf16_to_f(hi[j]));
  }
  ushort4 h4 = make_ushort4(hi[0], hi[1], hi[2], hi[3]);
  ushort4 l4 = make_ushort4(lo[0], lo[1], lo[2], lo[3]);
  *reinterpret_cast<ushort4*>(dst + base) = h4;
  if (mode == 0) {
    *reinterpret_cast<ushort4*>(dst + base + K_DIM) = h4;      // X: [hi|hi|lo]
    *reinterpret_cast<ushort4*>(dst + base + 2 * K_DIM) = l4;
  } else {
    *reinterpret_cast<ushort4*>(dst + base + K_DIM) = l4;      // W: [hi|lo|hi]
    *reinterpret_cast<ushort4*>(dst + base + 2 * K_DIM) = h4;
  }
}

// ---------------- MFMA GEMM, XCD-partitioned: 2 M-halves x 4 panel-chunks ----------------
// XCD k (= bid%8): M-half k&1 (A'half 3.1MB stays L2-resident), panel chunk k>>1
// (~98 panels streamed once). W' fetched 2x total instead of 8x.
#define SW 68  // padded row stride (words) for epilogue transpose

__global__ __launch_bounds__(512) void mfma_gemm_kernel(
    const unsigned short* __restrict__ Ap, const unsigned short* __restrict__ Bp,
    const float* __restrict__ Bv, float* __restrict__ C,
    unsigned* __restrict__ Tmax) {
  // XCD-aware decode (assumes round-robin bid->XCD)
  const int bid = blockIdx.x;
  const int xcd = bid & 7;
  const int slot = bid >> 3;            // 0..395
  const int h = xcd & 1, c = xcd >> 1;  // M-half, panel chunk
  const int s_c = c * 98 + (c > 0 ? 1 : 0);
  const int Pc = (c == 0) ? 99 : 98;    // 99+98+98+98 = 393
  const int p = slot >> 2;
  if (p >= Pc) return;
  const int bm = (h * 4 + (slot & 3)) * BM;
  const int bni = s_c + p;
  const int bn = bni * BN;

  __shared__ __align__(16) unsigned char lds[49152];
  const int tid = threadIdx.x;
  const int w = tid >> 6, lane = tid & 63;
  const int wr = w >> 1, wc = w & 1;  // 4M x 2N

  f32x4 acc[4][4] = {};

  for (int step = 0; step < NSTEP; ++step) {
    const int k0 = step * BKE;
#pragma unroll
    for (int l = 0; l < 4; ++l) {
      int pp = ((l * 512 + tid) << 4);
      int row = pp >> 7;
      int cb = (pp & 127) ^ ((row & 7) << 4);
      const unsigned short* ga = Ap + (size_t)(bm + row) * KP + k0 + (cb >> 1);
      __builtin_amdgcn_global_load_lds(
          (const __attribute__((address_space(1))) unsigned int*)ga,
          (__attribute__((address_space(3))) unsigned int*)(lds + pp), 16, 0, 0);
    }
#pragma unroll
    for (int l = 0; l < 2; ++l) {
      int pp = ((l * 512 + tid) << 4);
      int row = pp >> 7;
      int cb = (pp & 127) ^ ((row & 7) << 4);
      const unsigned short* gb = Bp + (size_t)(bn + row) * KP + k0 + (cb >> 1);
      __builtin_amdgcn_global_load_lds(
          (const __attribute__((address_space(1))) unsigned int*)gb,
          (__attribute__((address_space(3))) unsigned int*)(lds + 32768 + pp), 16, 0, 0);
    }
    __syncthreads();
#pragma unroll
    for (int kk = 0; kk < 2; ++kk) {
      const int kbyte = kk * 64 + ((lane >> 4) << 4);
      s16x8 a[4], b[4];
#pragma unroll
      for (int i = 0; i < 4; ++i) {
        int row = (wr << 6) + (i << 4) + (lane & 15);
        int byte = (row << 7) + (kbyte ^ ((row & 7) << 4));
        a[i] = *reinterpret_cast<const s16x8*>(lds + byte);
      }
#pragma unroll
      for (int j = 0; j < 4; ++j) {
        int row = (wc << 6) + (j << 4) + (lane & 15);
        int byte = (row << 7) + (kbyte ^ ((row & 7) << 4));
        b[j] = *reinterpret_cast<const s16x8*>(lds + 32768 + byte);
      }
#pragma unroll
      for (int i = 0; i < 4; ++i)
#pragma unroll
        for (int j = 0; j < 4; ++j) MFMA_16x16x32_BF16(acc[i][j], a[i], b[j]);
    }
    __syncthreads();
  }

  // ---- epilogue: per-wave LDS transpose, coalesced float4 stores, row maxima
  __syncthreads();
  float* wreg = reinterpret_cast<float*>(lds) + w * (16 * SW);
  float mx[4][4];
#pragma unroll
  for (int i = 0; i < 4; ++i)
#pragma unroll
    for (int r = 0; r < 4; ++r) mx[i][r] = -INFINITY;

#pragma unroll
  for (int i = 0; i < 4; ++i) {
#pragma unroll
    for (int j = 0; j < 4; ++j) {
      int n = bn + (wc << 6) + (j << 4) + (lane & 15);
      float bv = (n < V_DIM) ? Bv[n] : 0.f;
#pragma unroll
      for (int r = 0; r < 4; ++r) {
        float val = (acc[i][j][r] + bv) / TEMP;
        wreg[(((lane >> 4) << 2) + r) * SW + (j << 4) + (lane & 15)] = val;
        if (n < V_DIM) mx[i][r] = fmaxf(mx[i][r], val);
      }
    }
    int row = lane >> 2;
    int m = bm + (wr << 6) + (i << 4) + row;
#pragma unroll
    for (int it = 0; it < 4; ++it) {
      int c2 = ((lane & 3) << 2) + (it << 4);
      f32x4 v4 = *reinterpret_cast<const f32x4*>(wreg + row * SW + c2);
      int n4 = bn + (wc << 6) + c2;
      if (n4 + 3 < V_DIM) {
        *reinterpret_cast<f32x4*>(&C[(size_t)m * V_DIM + n4]) = v4;
      } else {
#pragma unroll
        for (int e = 0; e < 4; ++e)
          if (n4 + e < V_DIM) C[(size_t)m * V_DIM + n4 + e] = v4[e];
      }
    }
  }

  __syncthreads();
  unsigned* umax = reinterpret_cast<unsigned*>(lds);
  if (tid < BM) umax[tid] = 0;
  __syncthreads();
#pragma unroll
  for (int i = 0; i < 4; ++i) {
#pragma unroll
    for (int r = 0; r < 4; ++r) {
      float v = mx[i][r];
      v = fmaxf(v, __shfl_xor(v, 1));
      v = fmaxf(v, __shfl_xor(v, 2));
      v = fmaxf(v, __shfl_xor(v, 4));
      v = fmaxf(v, __shfl_xor(v, 8));
      if ((lane & 15) == 0)
        atomicMax(&umax[(wr << 6) + (i << 4) + ((lane >> 4) << 2) + r], f2key(v));
    }
  }
  __syncthreads();
  if (tid < BM) Tmax[(size_t)(bm + tid) * NBN + bni] = umax[tid];
}

// ---- per-row select: Tmax-guided gather + plain zero sweep ----
#define CAP 1024
#define SCAP 256

__global__ __launch_bounds__(256) void select_kernel(float* __restrict__ C,
                                                     const unsigned* __restrict__ Tmax) {
  const int row = blockIdx.x;
  float* rowp = C + (size_t)row * V_DIM;
  const int tid = threadIdx.x;

  __shared__ unsigned tk[NBN];
  __shared__ short ctile[NBN];
  __shared__ unsigned s_t50;
  __shared__ float cval[CAP];
  __shared__ int cidx[CAP];
  __shared__ float sval[SCAP];
  __shared__ int sidx[SCAP];
  __shared__ float pvals[SCAP];
  __shared__ int s_cnt, s_ntile, s_nsurv, s_kc;
  __shared__ float s_invZ;

  for (int i = tid; i < NBN; i += 256) tk[i] = Tmax[(size_t)row * NBN + i];
  if (tid == 0) { s_cnt = 0; s_ntile = 0; s_nsurv = 0; }
  __syncthreads();
  for (int i = tid; i < NBN; i += 256) {
    unsigned ki = tk[i];
    int r = 0;
    for (int j = 0; j < NBN; ++j) {
      unsigned kj = tk[j];
      r += (kj > ki) || (kj == ki && j < i);
    }
    if (r == TOPK - 1) s_t50 = ki;
  }
  __syncthreads();
  const unsigned t50 = s_t50;

  for (int i = tid; i < NBN; i += 256) {
    if (tk[i] >= t50) {
      int p = atomicAdd(&s_ntile, 1);
      ctile[p] = (short)i;
    }
  }
  __syncthreads();
  const int ntile = s_ntile;

  for (int e = tid; e < ntile * BN; e += 256) {
    int ti = ctile[e >> 7];
    int n = ti * BN + (e & 127);
    if (n < V_DIM) {
      float l = rowp[n];
      if (f2key(l) >= t50) {
        int p = atomicAdd(&s_cnt, 1);
        if (p < CAP) { cval[p] = l; cidx[p] = n; }
      }
    }
  }
  __syncthreads();
  const int n = min(s_cnt, CAP);

  // zero the whole row: pure stream write
  {
    const f32x4 z4 = {0.f, 0.f, 0.f, 0.f};
    const int NQ = V_DIM >> 2;
    f32x4* rp4 = reinterpret_cast<f32x4*>(rowp);
    for (int q = tid; q < NQ; q += 256) rp4[q] = z4;
    if (tid == 0) rowp[V_DIM - 1] = 0.f;
  }

  // parallel stable rank (val desc, idx asc)
  for (int i = tid; i < n; i += 256) {
    float vi = cval[i];
    int xi = cidx[i];
    int r = 0;
    for (int j = 0; j < n; ++j) {
      float vj = cval[j];
      if (vj > vi || (vj == vi && cidx[j] < xi)) ++r;
    }
    if (r < SCAP) { sval[r] = vi; sidx[r] = xi; }
  }
  __syncthreads();

  const float t = sval[TOPK - 1];
  for (int i = tid; i < n; i += 256)
    if (cval[i] >= t) atomicAdd(&s_nsurv, 1);
  __syncthreads();
  const int nsurv = min(s_nsurv, SCAP);

  const float m = sval[0];
  for (int i = tid; i < nsurv; i += 256) pvals[i] = expf(sval[i] - m);
  __syncthreads();
  if (tid == 0) {
    float Z0 = 0.f;
    for (int i = 0; i < nsurv; ++i) Z0 += pvals[i];
    float cum = 0.f;
    int kc = 0;
    float Z2 = 0.f;
    for (int i = 0; i < nsurv; ++i) {
      cum += pvals[i] / Z0;
      if (cum > TOPP) break;
      kc = i + 1;
      Z2 += pvals[i];
    }
    s_kc = kc;
    s_invZ = (kc > 0) ? (1.f / Z2) : 0.f;
  }
  __syncthreads();
  const int kc = s_kc;
  const float invZ = s_invZ;

  for (int q = tid; q < kc; q += 256) {
    int r = -1, less = 0;
    for (int s = 0; s < nsurv; ++s) {
      if (sidx[s] == q) r = s;
      if (sidx[s] < q) ++less;
    }
    int rank = (r >= 0) ? r : (nsurv + q - less);
    rowp[rank] = pvals[q] * invZ;
  }
}

// ----------------------------- launcher ------------------------------
extern "C" void kernel_launch(void* const* d_in, const int* in_sizes, int n_in,
                              void* d_out, int out_size, void* d_ws, size_t ws_size,
                              hipStream_t stream) {
  const float* X = (const float*)d_in[0];
  const float* W = (const float*)d_in[1];
  const float* Bv = (const float*)d_in[2];
  float* C = (float*)d_out;

  unsigned short* Xp = (unsigned short*)d_ws;
  unsigned short* Wp = Xp + (size_t)M_TOT * KP;
  unsigned* Tmax = (unsigned*)(Wp + (size_t)NPAD * KP);

  conv_kernel<<<(NQX + NQW + 255) / 256, 256, 0, stream>>>(X, W, Xp, Wp);
  mfma_gemm_kernel<<<8 * 396, 512, 0, stream>>>(Xp, Wp, Bv, C, Tmax);
  select_kernel<<<M_TOT, 256, 0, stream>>>(C, Tmax);
}

// Round 13
// 638.221 us; speedup vs baseline: 1.0362x; 1.0362x over previous
//
#include <hip/hip_runtime.h>
#include <math.h>

// Problem constants
#define TEMP 0.7f
#define TOPK 50
#define TOPP 0.9f
#define M_TOT 2048      // B*S
#define K_DIM 512       // H
#define V_DIM 50257     // vocab
#define NPAD 50304      // 393*128
#define KP 1536         // 3*K_DIM: [hi|hi|lo] x [hi|lo|hi]
#define BM 256
#define BN 128
#define BKE 64
#define NSTEP (KP / BKE)
#define NBN (NPAD / BN)  // 393 N-tiles
#define NBM (M_TOT / BM) // 8 M-tiles

typedef short s16x8 __attribute__((ext_vector_type(8)));
typedef float f32x4 __attribute__((ext_vector_type(4)));

#define MFMA_16x16x32_BF16(acc, va, vb) \
  asm("v_mfma_f32_16x16x32_bf16 %0, %1, %2, %0" : "+v"(acc) : "v"(va), "v"(vb))

__device__ __forceinline__ unsigned short bf16_rn(float x) {
  unsigned u = __float_as_uint(x);
  unsigned r = u + 0x7FFFu + ((u >> 16) & 1u);
  return (unsigned short)(r >> 16);
}
__device__ __forceinline__ float bf16_to_f(unsigned short h) {
  return __uint_as_float(((unsigned)h) << 16);
}
__device__ __forceinline__ unsigned f2key(float f) {
  unsigned u = __float_as_uint(f);
  return (u & 0x80000000u) ? ~u : (u | 0x80000000u);
}

// ------- fused conversion + optional d_out pre-zero (all BW-bound streams) -------
#define NQX (M_TOT * (K_DIM / 4))
#define NQW (NPAD * (K_DIM / 4))
#define NZQ ((M_TOT * V_DIM) / 4)  // exact: 2048*50257/4

__global__ __launch_bounds__(256) void conv_kernel(const float* __restrict__ X,
                                                   const float* __restrict__ W,
                                                   unsigned short* __restrict__ Xp,
                                                   unsigned short* __restrict__ Wp,
                                                   float* __restrict__ Z, int nzq) {
  int idx = blockIdx.x * 256 + threadIdx.x;
  if (idx >= NQX + NQW) {
    int zi = idx - (NQX + NQW);
    if (zi < nzq) {
      const f32x4 z4 = {0.f, 0.f, 0.f, 0.f};
      reinterpret_cast<f32x4*>(Z)[zi] = z4;
    }
    return;
  }
  float4 v;
  unsigned short* dst;
  size_t base;
  int mode;
  if (idx < NQX) {
    int row = idx >> 7, q = idx & 127;
    v = reinterpret_cast<const float4*>(X)[idx];
    dst = Xp;
    base = (size_t)row * KP + q * 4;
    mode = 0;
  } else {
    int wi = idx - NQX;
    int row = wi >> 7, q = wi & 127;
    v = make_float4(0.f, 0.f, 0.f, 0.f);
    if (row < V_DIM) v = reinterpret_cast<const float4*>(W)[(size_t)row * 128 + q];
    dst = Wp;
    base = (size_t)row * KP + q * 4;
    mode = 1;
  }
  float vv[4] = {v.x, v.y, v.z, v.w};
  unsigned short hi[4], lo[4];
#pragma unroll
  for (int j = 0; j < 4; ++j) {
    hi[j] = bf16_rn(vv[j]);
    lo[j] = bf16_rn(vv[j] - bf16_to_f(hi[j]));
  }
  ushort4 h4 = make_ushort4(hi[0], hi[1], hi[2], hi[3]);
  ushort4 l4 = make_ushort4(lo[0], lo[1], lo[2], lo[3]);
  *reinterpret_cast<ushort4*>(dst + base) = h4;
  if (mode == 0) {
    *reinterpret_cast<ushort4*>(dst + base + K_DIM) = h4;      // X: [hi|hi|lo]
    *reinterpret_cast<ushort4*>(dst + base + 2 * K_DIM) = l4;
  } else {
    *reinterpret_cast<ushort4*>(dst + base + K_DIM) = l4;      // W: [hi|lo|hi]
    *reinterpret_cast<ushort4*>(dst + base + 2 * K_DIM) = h4;
  }
}

// ---------------- MFMA GEMM (r11 config, best measured) ----------------
#define SW 68  // padded row stride (words) for epilogue transpose

__global__ __launch_bounds__(512) void mfma_gemm_kernel(
    const unsigned short* __restrict__ Ap, const unsigned short* __restrict__ Bp,
    const float* __restrict__ Bv, float* __restrict__ C,
    unsigned* __restrict__ Tmax) {
  __shared__ __align__(16) unsigned char lds[49152];
  const int tid = threadIdx.x;
  const int w = tid >> 6, lane = tid & 63;
  const int bm = blockIdx.x * BM;
  const int bni = blockIdx.y;
  const int bn = bni * BN;
  const int wr = w >> 1, wc = w & 1;  // 4M x 2N

  f32x4 acc[4][4] = {};

  for (int step = 0; step < NSTEP; ++step) {
    const int k0 = step * BKE;
#pragma unroll
    for (int l = 0; l < 4; ++l) {
      int pp = ((l * 512 + tid) << 4);
      int row = pp >> 7;
      int cb = (pp & 127) ^ ((row & 7) << 4);
      const unsigned short* ga = Ap + (size_t)(bm + row) * KP + k0 + (cb >> 1);
      __builtin_amdgcn_global_load_lds(
          (const __attribute__((address_space(1))) unsigned int*)ga,
          (__attribute__((address_space(3))) unsigned int*)(lds + pp), 16, 0, 0);
    }
#pragma unroll
    for (int l = 0; l < 2; ++l) {
      int pp = ((l * 512 + tid) << 4);
      int row = pp >> 7;
      int cb = (pp & 127) ^ ((row & 7) << 4);
      const unsigned short* gb = Bp + (size_t)(bn + row) * KP + k0 + (cb >> 1);
      __builtin_amdgcn_global_load_lds(
          (const __attribute__((address_space(1))) unsigned int*)gb,
          (__attribute__((address_space(3))) unsigned int*)(lds + 32768 + pp), 16, 0, 0);
    }
    __syncthreads();
#pragma unroll
    for (int kk = 0; kk < 2; ++kk) {
      const int kbyte = kk * 64 + ((lane >> 4) << 4);
      s16x8 a[4], b[4];
#pragma unroll
      for (int i = 0; i < 4; ++i) {
        int row = (wr << 6) + (i << 4) + (lane & 15);
        int byte = (row << 7) + (kbyte ^ ((row & 7) << 4));
        a[i] = *reinterpret_cast<const s16x8*>(lds + byte);
      }
#pragma unroll
      for (int j = 0; j < 4; ++j) {
        int row = (wc << 6) + (j << 4) + (lane & 15);
        int byte = (row << 7) + (kbyte ^ ((row & 7) << 4));
        b[j] = *reinterpret_cast<const s16x8*>(lds + 32768 + byte);
      }
#pragma unroll
      for (int i = 0; i < 4; ++i)
#pragma unroll
        for (int j = 0; j < 4; ++j) MFMA_16x16x32_BF16(acc[i][j], a[i], b[j]);
    }
    __syncthreads();
  }

  // ---- epilogue: per-wave LDS transpose, coalesced float4 stores, row maxima
  __syncthreads();
  float* wreg = reinterpret_cast<float*>(lds) + w * (16 * SW);
  float mx[4][4];
#pragma unroll
  for (int i = 0; i < 4; ++i)
#pragma unroll
    for (int r = 0; r < 4; ++r) mx[i][r] = -INFINITY;

#pragma unroll
  for (int i = 0; i < 4; ++i) {
#pragma unroll
    for (int j = 0; j < 4; ++j) {
      int n = bn + (wc << 6) + (j << 4) + (lane & 15);
      float bv = (n < V_DIM) ? Bv[n] : 0.f;
#pragma unroll
      for (int r = 0; r < 4; ++r) {
        float val = (acc[i][j][r] + bv) / TEMP;
        wreg[(((lane >> 4) << 2) + r) * SW + (j << 4) + (lane & 15)] = val;
        if (n < V_DIM) mx[i][r] = fmaxf(mx[i][r], val);
      }
    }
    int row = lane >> 2;
    int m = bm + (wr << 6) + (i << 4) + row;
#pragma unroll
    for (int it = 0; it < 4; ++it) {
      int c2 = ((lane & 3) << 2) + (it << 4);
      f32x4 v4 = *reinterpret_cast<const f32x4*>(wreg + row * SW + c2);
      int n4 = bn + (wc << 6) + c2;
      if (n4 + 3 < V_DIM) {
        *reinterpret_cast<f32x4*>(&C[(size_t)m * V_DIM + n4]) = v4;
      } else {
#pragma unroll
        for (int e = 0; e < 4; ++e)
          if (n4 + e < V_DIM) C[(size_t)m * V_DIM + n4 + e] = v4[e];
      }
    }
  }

  __syncthreads();
  unsigned* umax = reinterpret_cast<unsigned*>(lds);
  if (tid < BM) umax[tid] = 0;
  __syncthreads();
#pragma unroll
  for (int i = 0; i < 4; ++i) {
#pragma unroll
    for (int r = 0; r < 4; ++r) {
      float v = mx[i][r];
      v = fmaxf(v, __shfl_xor(v, 1));
      v = fmaxf(v, __shfl_xor(v, 2));
      v = fmaxf(v, __shfl_xor(v, 4));
      v = fmaxf(v, __shfl_xor(v, 8));
      if ((lane & 15) == 0)
        atomicMax(&umax[(wr << 6) + (i << 4) + ((lane >> 4) << 2) + r], f2key(v));
    }
  }
  __syncthreads();
  if (tid < BM) Tmax[(size_t)(bm + tid) * NBN + bni] = umax[tid];
}

// ---- per-row select: Tmax-guided gather (from Lg) + scatter (to C) ----
// do_zero=1 (fallback, Lg==C): zero the row between gather and scatter.
#define CAP 1024
#define SCAP 256

__global__ __launch_bounds__(256) void select_kernel(const float* __restrict__ Lg,
                                                     float* __restrict__ C,
                                                     const unsigned* __restrict__ Tmax,
                                                     int do_zero) {
  const int row = blockIdx.x;
  const float* rowin = Lg + (size_t)row * V_DIM;
  float* rowout = C + (size_t)row * V_DIM;
  const int tid = threadIdx.x;

  __shared__ unsigned tk[NBN];
  __shared__ short ctile[NBN];
  __shared__ unsigned s_t50;
  __shared__ float cval[CAP];
  __shared__ int cidx[CAP];
  __shared__ float sval[SCAP];
  __shared__ int sidx[SCAP];
  __shared__ float pvals[SCAP];
  __shared__ int s_cnt, s_ntile, s_nsurv, s_kc;
  __shared__ float s_invZ;

  for (int i = tid; i < NBN; i += 256) tk[i] = Tmax[(size_t)row * NBN + i];
  if (tid == 0) { s_cnt = 0; s_ntile = 0; s_nsurv = 0; }
  __syncthreads();
  for (int i = tid; i < NBN; i += 256) {
    unsigned ki = tk[i];
    int r = 0;
    for (int j = 0; j < NBN; ++j) {
      unsigned kj = tk[j];
      r += (kj > ki) || (kj == ki && j < i);
    }
    if (r == TOPK - 1) s_t50 = ki;
  }
  __syncthreads();
  const unsigned t50 = s_t50;

  for (int i = tid; i < NBN; i += 256) {
    if (tk[i] >= t50) {
      int p = atomicAdd(&s_ntile, 1);
      ctile[p] = (short)i;
    }
  }
  __syncthreads();
  const int ntile = s_ntile;

  for (int e = tid; e < ntile * BN; e += 256) {
    int ti = ctile[e >> 7];
    int n = ti * BN + (e & 127);
    if (n < V_DIM) {
      float l = rowin[n];
      if (f2key(l) >= t50) {
        int p = atomicAdd(&s_cnt, 1);
        if (p < CAP) { cval[p] = l; cidx[p] = n; }
      }
    }
  }
  __syncthreads();
  const int n = min(s_cnt, CAP);

  if (do_zero) {  // fallback path: logits live in C; zero the row now
    const f32x4 z4 = {0.f, 0.f, 0.f, 0.f};
    const int NQ = V_DIM >> 2;
    f32x4* rp4 = reinterpret_cast<f32x4*>(rowout);
    for (int q = tid; q < NQ; q += 256) rp4[q] = z4;
    if (tid == 0) rowout[V_DIM - 1] = 0.f;
  }

  // parallel stable rank (val desc, idx asc)
  for (int i = tid; i < n; i += 256) {
    float vi = cval[i];
    int xi = cidx[i];
    int r = 0;
    for (int j = 0; j < n; ++j) {
      float vj = cval[j];
      if (vj > vi || (vj == vi && cidx[j] < xi)) ++r;
    }
    if (r < SCAP) { sval[r] = vi; sidx[r] = xi; }
  }
  __syncthreads();

  const float t = sval[TOPK - 1];
  for (int i = tid; i < n; i += 256)
    if (cval[i] >= t) atomicAdd(&s_nsurv, 1);
  __syncthreads();
  const int nsurv = min(s_nsurv, SCAP);

  const float m = sval[0];
  for (int i = tid; i < nsurv; i += 256) pvals[i] = expf(sval[i] - m);
  __syncthreads();
  if (tid == 0) {
    float Z0 = 0.f;
    for (int i = 0; i < nsurv; ++i) Z0 += pvals[i];
    float cum = 0.f;
    int kc = 0;
    float Z2 = 0.f;
    for (int i = 0; i < nsurv; ++i) {
      cum += pvals[i] / Z0;
      if (cum > TOPP) break;
      kc = i + 1;
      Z2 += pvals[i];
    }
    s_kc = kc;
    s_invZ = (kc > 0) ? (1.f / Z2) : 0.f;
  }
  __syncthreads();
  const int kc = s_kc;
  const float invZ = s_invZ;

  for (int q = tid; q < kc; q += 256) {
    int r = -1, less = 0;
    for (int s = 0; s < nsurv; ++s) {
      if (sidx[s] == q) r = s;
      if (sidx[s] < q) ++less;
    }
    int rank = (r >= 0) ? r : (nsurv + q - less);
    rowout[rank] = pvals[q] * invZ;
  }
}

// ----------------------------- launcher ------------------------------
extern "C" void kernel_launch(void* const* d_in, const int* in_sizes, int n_in,
                              void* d_out, int out_size, void* d_ws, size_t ws_size,
                              hipStream_t stream) {
  const float* X = (const float*)d_in[0];
  const float* W = (const float*)d_in[1];
  const float* Bv = (const float*)d_in[2];
  float* C = (float*)d_out;

  unsigned short* Xp = (unsigned short*)d_ws;
  unsigned short* Wp = Xp + (size_t)M_TOT * KP;
  unsigned* Tmax = (unsigned*)(Wp + (size_t)NPAD * KP);
  float* Lws = (float*)(Tmax + (size_t)M_TOT * NBN);

  const size_t need_big = (size_t)((char*)(Lws + (size_t)M_TOT * V_DIM) - (char*)d_ws);
  const int big = (ws_size >= need_big);

  float* Lg = big ? Lws : C;  // logits target
  const int nzq = big ? NZQ : 0;

  conv_kernel<<<(NQX + NQW + nzq + 255) / 256, 256, 0, stream>>>(X, W, Xp, Wp, C, nzq);
  dim3 g(NBM, NBN);  // M fastest: 8 blocks share a B panel
  mfma_gemm_kernel<<<g, 512, 0, stream>>>(Xp, Wp, Bv, Lg, Tmax);
  select_kernel<<<M_TOT, 256, 0, stream>>>(Lg, C, Tmax, big ? 0 : 1);
}